// Round 8
// baseline (605.068 us; speedup 1.0000x reference)
//
#include <hip/hip_runtime.h>
#include <stdint.h>

#define D_FEAT 128
#define TOPK   128
#define KSPLIT 384            // 3 x 128 (h|h|l) . (h|l|h)
#define SCALE  4096.0f
#define SCALE2 16777216.0f    // SCALE^2 (2^24, exact)

typedef float    f32x4 __attribute__((ext_vector_type(4)));
typedef _Float16 half8 __attribute__((ext_vector_type(8)));

// ---------------- squared norms (unscaled f32) ----------------
__global__ __launch_bounds__(256) void sqnorm_kernel(const float* __restrict__ X,
                                                     float* __restrict__ out, int rows) {
    int r = blockIdx.x * 256 + threadIdx.x;
    if (r >= rows) return;
    const float4* p = (const float4*)(X + (size_t)r * D_FEAT);
    float s = 0.f;
    #pragma unroll
    for (int i = 0; i < D_FEAT / 4; ++i) {
        float4 v = p[i];
        s += v.x * v.x + v.y * v.y + v.z * v.z + v.w * v.w;
    }
    out[r] = s;
}

// ---------------- f32 -> scaled f16 (hi,lo) split, K-concatenated ----------------
__global__ __launch_bounds__(128) void split_kernel(const float* __restrict__ X,
                                                    unsigned short* __restrict__ out,
                                                    int isA) {
    int row = blockIdx.x;
    int k   = threadIdx.x;
    float a = X[(size_t)row * D_FEAT + k] * SCALE;
    _Float16 h = (_Float16)a;
    float hf = (float)h;
    _Float16 l = (_Float16)(a - hf);
    unsigned short hu, lu;
    __builtin_memcpy(&hu, &h, 2);
    __builtin_memcpy(&lu, &l, 2);
    size_t b = (size_t)row * KSPLIT;
    out[b + k]              = hu;
    out[b + D_FEAT + k]     = isA ? hu : lu;
    out[b + 2 * D_FEAT + k] = isA ? lu : hu;
}

// ---------------- MFMA distance kernel (gload_lds + dbuf) -> 16-bit keys ----------------
#define BM 128
#define BN 256
#define BKS 32                 // 32 halves = 64 B per row per slab
#define NSLAB (KSPLIT / BKS)   // 12
#define ASLOT (BM * 4)         // 512 16B-slots
#define BSLOT (BN * 4)         // 1024 16B-slots
#define BUFELEM ((ASLOT + BSLOT) * 8)   // u16 elems per buffer (12288 = 24 KB)

static __device__ __forceinline__ half8 lds_read_half8(const unsigned short* p) {
    half8 r;
    __builtin_memcpy(&r, p, 16);
    return r;
}

static __device__ __forceinline__ void gload_lds16(const unsigned short* g, unsigned short* l) {
    __builtin_amdgcn_global_load_lds(
        (const __attribute__((address_space(1))) unsigned int*)g,
        (__attribute__((address_space(3))) unsigned int*)l, 16, 0, 0);
}

// stage one BK=32 slab of A(128 rows) + B(256 rows) into buf via global_load_lds.
// LDS dest is linear in slot = row*4 + c ; GLOBAL source chunk is pre-swizzled
// sc = c ^ ((row>>1)&3) so compute-side ds_read_b128 (same XOR) is conflict-free.
static __device__ __forceinline__ void stage_slab(
        const unsigned short* __restrict__ Asp,
        const unsigned short* __restrict__ Bsp,
        unsigned short* buf, int aRowBase, int bRowBase, int kt, int w, int l) {
    {   // A: 512 slots, one wave-round
        int slot = w * 64 + l;
        int row = slot >> 2, c = slot & 3;
        int sc  = c ^ ((row >> 1) & 3);
        gload_lds16(Asp + (size_t)(aRowBase + row) * KSPLIT + kt + sc * 8,
                    buf + (size_t)(w * 64) * 8);
    }
    #pragma unroll
    for (int r = 0; r < 2; ++r) {   // B: 1024 slots, two wave-rounds
        int slot = r * 512 + w * 64 + l;
        int row = slot >> 2, c = slot & 3;
        int sc  = c ^ ((row >> 1) & 3);
        gload_lds16(Bsp + (size_t)(bRowBase + row) * KSPLIT + kt + sc * 8,
                    buf + ASLOT * 8 + (size_t)(r * 512 + w * 64) * 8);
    }
}

__global__ __launch_bounds__(512, 4) void dist_mfma_kernel(
        const unsigned short* __restrict__ Asp,   // [n][384]
        const unsigned short* __restrict__ Bsp,   // [N][384]
        const float* __restrict__ x2,
        const float* __restrict__ y2,
        unsigned short* __restrict__ keyout,      // row-major [chunk][N]
        int q0, int N, int rowsM) {
    __shared__ __align__(16) unsigned short sh[2 * BUFELEM];   // 48 KB
    unsigned short* bufA = sh;
    unsigned short* bufB = sh + BUFELEM;

    // XCD-aware swizzle: column-major per XCD (contiguous N-band per XCD)
    const int nwg = (N / BN) * rowsM;      // multiple of 8
    const int cpx = nwg >> 3;
    const int bid = blockIdx.x;
    const int swz = (bid & 7) * cpx + (bid >> 3);
    const int col   = swz / rowsM;
    const int mrowi = swz - col * rowsM;
    const int nb = col * BN;
    const int mb = mrowi * BM;

    const int tid  = threadIdx.x;
    const int lane = tid & 63;
    const int w    = tid >> 6;
    const int wr   = w >> 2, wc = w & 3;   // 2 x 4 wave grid, 64x64 per wave

    f32x4 acc[4][4];
    #pragma unroll
    for (int i = 0; i < 4; ++i)
        #pragma unroll
        for (int j = 0; j < 4; ++j)
            acc[i][j] = (f32x4){0.f, 0.f, 0.f, 0.f};

    stage_slab(Asp, Bsp, bufA, q0 + mb, nb, 0, w, lane);

    const int c = lane >> 4;               // K chunk 0..3
    for (int s = 0; s < NSLAB; ++s) {
        __syncthreads();                   // drains stage(s) + compute(s-1) done
        unsigned short* cur = (s & 1) ? bufB : bufA;
        unsigned short* nxt = (s & 1) ? bufA : bufB;
        if (s + 1 < NSLAB)
            stage_slab(Asp, Bsp, nxt, q0 + mb, nb, (s + 1) * BKS, w, lane);  // DMA overlaps MFMA
        const unsigned short* Acur = cur;
        const unsigned short* Bcur = cur + ASLOT * 8;
        half8 af[4], bf[4];
        #pragma unroll
        for (int f = 0; f < 4; ++f) {
            int m  = wr * 64 + f * 16 + (lane & 15);
            af[f] = lds_read_half8(Acur + (size_t)(m * 4 + (c ^ ((m >> 1) & 3))) * 8);
            int nn = wc * 64 + f * 16 + (lane & 15);
            bf[f] = lds_read_half8(Bcur + (size_t)(nn * 4 + (c ^ ((nn >> 1) & 3))) * 8);
        }
        #pragma unroll
        for (int i = 0; i < 4; ++i)
            #pragma unroll
            for (int j = 0; j < 4; ++j)
                acc[i][j] = __builtin_amdgcn_mfma_f32_16x16x32_f16(af[i], bf[j], acc[i][j], 0, 0, 0);
    }

    // ---- epilogue: direct key16 stores (row-major) ----
    float x2v[16];
    #pragma unroll
    for (int fi = 0; fi < 4; ++fi)
        #pragma unroll
        for (int r = 0; r < 4; ++r)
            x2v[fi * 4 + r] = x2[q0 + mb + wr * 64 + fi * 16 + (lane >> 4) * 4 + r];
    #pragma unroll
    for (int fj = 0; fj < 4; ++fj) {
        float yv = y2[nb + wc * 64 + fj * 16 + (lane & 15)];
        #pragma unroll
        for (int fi = 0; fi < 4; ++fi) {
            #pragma unroll
            for (int r = 0; r < 4; ++r) {
                float d = fmaf(-2.0f, acc[fi][fj][r], SCALE2 * (x2v[fi * 4 + r] + yv));
                d = fmaxf(d, 0.0f);
                int m  = mb + wr * 64 + fi * 16 + (lane >> 4) * 4 + r;
                int nn = nb + wc * 64 + fj * 16 + (lane & 15);
                keyout[(size_t)m * N + nn] = (unsigned short)(__float_as_uint(d) >> 15);
            }
        }
    }
}

// ---------------- selection + vote: keys staged in LDS (v5) ----------------
// One 1024-thread block per query. Whole 128 KB key row lives in LDS; the
// 8x3-probe search re-scans LDS (ds_read_b128, conflict-free) instead of
// scratch/L2. Exact f64 tie ranking at the 16-bit cutoff unchanged.
#define SEL_T  1024
#define NKEYS  65536
#define NWORD4 (NKEYS / 8)      // 8192 uint4 entries
#define CAP    1536

__global__ __launch_bounds__(SEL_T) void select5_kernel(
        const unsigned short* __restrict__ keys,
        const float* __restrict__ labels,
        const float* __restrict__ Q, const float* __restrict__ Dta,
        int* __restrict__ out, int q0, int N, int n_total, int out_size) {
    __shared__ __align__(16) unsigned short kbuf[NKEYS];   // 128 KB
    __shared__ double       cval[CAP];                     // 12 KB
    __shared__ unsigned int ckey[CAP];                     // 6 KB
    __shared__ unsigned int red[2][3][16];
    __shared__ unsigned int tot[2][3];
    __shared__ unsigned int mcnt, votes_sh;

    const int tid = threadIdx.x;
    const int qi  = q0 + blockIdx.x;
    const unsigned short* row = keys + (size_t)blockIdx.x * N;

    // ---- stage key row into LDS (global_load_lds, linear dest) ----
    #pragma unroll
    for (int r = 0; r < 8; ++r) {
        gload_lds16(row + (size_t)(r * 1024 + tid) * 8,
                    kbuf + (size_t)(r * 1024 + (tid & ~63)) * 8);
    }
    if (tid == 0) { mcnt = 0; votes_sh = 0; }
    __syncthreads();

    const uint4* k4 = (const uint4*)kbuf;

    // ---- 8 passes x 3 probes: resolve 16-bit tau ----
    uint32_t lo = 0, hi = 65536, base = 0;
    #pragma unroll 1
    for (int pass = 0; pass < 8; ++pass) {
        uint32_t qs = (hi - lo) >> 2;
        uint32_t p1 = lo + qs, p2 = p1 + qs, p3 = p2 + qs;
        uint32_t c1 = 0, c2 = 0, c3 = 0;
        #pragma unroll
        for (int r = 0; r < 8; ++r) {
            uint4 v = k4[r * 1024 + tid];
            #pragma unroll
            for (int w2 = 0; w2 < 4; ++w2) {
                uint32_t p = (w2 == 0) ? v.x : (w2 == 1) ? v.y : (w2 == 2) ? v.z : v.w;
                uint32_t a = p & 0xFFFFu, b = p >> 16;
                c1 += (a < p1) + (b < p1);
                c2 += (a < p2) + (b < p2);
                c3 += (a < p3) + (b < p3);
            }
        }
        #pragma unroll
        for (int off = 32; off > 0; off >>= 1) {
            c1 += __shfl_down(c1, off, 64);
            c2 += __shfl_down(c2, off, 64);
            c3 += __shfl_down(c3, off, 64);
        }
        int bsel = pass & 1;
        if ((tid & 63) == 0) {
            int ww = tid >> 6;
            red[bsel][0][ww] = c1; red[bsel][1][ww] = c2; red[bsel][2][ww] = c3;
        }
        __syncthreads();
        if (tid < 48) {
            int g = tid >> 4, i = tid & 15;
            unsigned int v = red[bsel][g][i];
            v += __shfl_xor(v, 1, 64);
            v += __shfl_xor(v, 2, 64);
            v += __shfl_xor(v, 4, 64);
            v += __shfl_xor(v, 8, 64);
            if (i == 0) tot[bsel][g] = v;
        }
        __syncthreads();
        uint32_t t1 = tot[bsel][0], t2 = tot[bsel][1], t3 = tot[bsel][2];
        if      (t1 >= TOPK) { hi = p1; }
        else if (t2 >= TOPK) { lo = p1; hi = p2; base = t1; }
        else if (t3 >= TOPK) { lo = p2; hi = p3; base = t2; }
        else                 { lo = p3;          base = t3; }
    }
    const uint32_t tau    = lo;
    const uint32_t t_take = TOPK - base;

    // ---- vote below tau; gather tau-ties with exact f64 distances ----
    uint32_t votes = 0;
    #pragma unroll 1
    for (int r = 0; r < 8; ++r) {
        uint4 v = k4[r * 1024 + tid];
        #pragma unroll
        for (int w2 = 0; w2 < 4; ++w2) {
            uint32_t p = (w2 == 0) ? v.x : (w2 == 1) ? v.y : (w2 == 2) ? v.z : v.w;
            #pragma unroll
            for (int h = 0; h < 2; ++h) {
                uint32_t key = (h == 0) ? (p & 0xFFFFu) : (p >> 16);
                if (key <= tau) {
                    int j = (r * 1024 + tid) * 8 + w2 * 2 + h;
                    if (key < tau) {
                        votes += (labels[j] > 0.5f) ? 1u : 0u;
                    } else {
                        unsigned int lab = (labels[j] > 0.5f) ? 0x80000000u : 0u;
                        unsigned int e = atomicAdd(&mcnt, 1u);
                        if (e < CAP) {
                            const float* qp = Q   + (size_t)qi * D_FEAT;
                            const float* dp = Dta + (size_t)j  * D_FEAT;
                            double sacc = 0.0;
                            for (int k = 0; k < D_FEAT; ++k) {
                                double df = (double)qp[k] - (double)dp[k];
                                sacc = fma(df, df, sacc);
                            }
                            cval[e] = sacc;
                            ckey[e] = (unsigned int)j | lab;
                        }
                    }
                }
            }
        }
    }
    #pragma unroll
    for (int off = 32; off > 0; off >>= 1)
        votes += __shfl_down(votes, off, 64);
    if ((tid & 63) == 0 && votes) atomicAdd(&votes_sh, votes);
    __syncthreads();

    unsigned int m = mcnt; if (m > CAP) m = CAP;
    for (unsigned int e = tid; e < m; e += SEL_T) {
        double       ve = cval[e];
        unsigned int ke = ckey[e];
        unsigned int ie = ke & 0x7FFFFFFFu;
        unsigned int rank = 0;
        for (unsigned int f = 0; f < m; ++f) {
            double       vf = cval[f];
            unsigned int jf = ckey[f] & 0x7FFFFFFFu;
            rank += (vf < ve || (vf == ve && jf < ie)) ? 1u : 0u;
        }
        if (rank < t_take && (ke & 0x80000000u)) atomicAdd(&votes_sh, 1u);
    }
    __syncthreads();

    if (tid == 0) {
        unsigned int v1 = votes_sh;
        out[qi] = (v1 > TOPK / 2) ? 1 : 0;          // 64/64 tie -> class 0
        if (qi == 0 && out_size > n_total) out[n_total] = 0;
    }
}

// ---------------- host ----------------
extern "C" void kernel_launch(void* const* d_in, const int* in_sizes, int n_in,
                              void* d_out, int out_size, void* d_ws, size_t ws_size,
                              hipStream_t stream) {
    const float* Q   = (const float*)d_in[0];
    const float* Dta = (const float*)d_in[1];
    const float* L   = (const float*)d_in[2];
    const int n = in_sizes[0] / D_FEAT;    // 2048
    const int N = in_sizes[1] / D_FEAT;    // 65536
    int* out = (int*)d_out;

    char* ws = (char*)d_ws;
    size_t off = 0;
    float* y2 = (float*)(ws + off); off += (((size_t)N * 4) + 255) & ~(size_t)255;
    float* x2 = (float*)(ws + off); off += (((size_t)n * 4) + 255) & ~(size_t)255;
    unsigned short* Asp = (unsigned short*)(ws + off); off += (((size_t)n * KSPLIT * 2) + 255) & ~(size_t)255;
    unsigned short* Bsp = (unsigned short*)(ws + off); off += (((size_t)N * KSPLIT * 2) + 255) & ~(size_t)255;
    unsigned short* keybuf = (unsigned short*)(ws + off);
    size_t avail = (ws_size > off) ? (ws_size - off) : 0;

    long maxQ = (long)(avail / ((size_t)N * 2));
    int chunkQ;
    if (maxQ >= n) chunkQ = n;
    else { chunkQ = (int)((maxQ / BM) * BM); if (chunkQ < BM) chunkQ = BM; }

    sqnorm_kernel<<<dim3((N + 255) / 256), dim3(256), 0, stream>>>(Dta, y2, N);
    sqnorm_kernel<<<dim3((n + 255) / 256), dim3(256), 0, stream>>>(Q, x2, n);
    split_kernel<<<dim3(n), dim3(128), 0, stream>>>(Q, Asp, 1);
    split_kernel<<<dim3(N), dim3(128), 0, stream>>>(Dta, Bsp, 0);

    for (int q0 = 0; q0 < n; q0 += chunkQ) {
        int q = n - q0; if (q > chunkQ) q = chunkQ;
        int rowsM = q / BM;
        int nwg = (N / BN) * rowsM;
        dist_mfma_kernel<<<dim3(nwg), dim3(512), 0, stream>>>(Asp, Bsp, x2, y2, keybuf, q0, N, rowsM);
        select5_kernel<<<dim3(q), dim3(SEL_T), 0, stream>>>(keybuf, L, Q, Dta, out, q0, N, n, out_size);
    }
}

// Round 9
// 433.447 us; speedup vs baseline: 1.3959x; 1.3959x over previous
//
#include <hip/hip_runtime.h>
#include <stdint.h>

#define D_FEAT 128
#define TOPK   128
#define KSPLIT 384            // 3 x 128 (h|h|l) . (h|l|h)
#define SCALE  4096.0f
#define SCALE2 16777216.0f    // SCALE^2 (2^24, exact)

typedef float    f32x4 __attribute__((ext_vector_type(4)));
typedef _Float16 half8 __attribute__((ext_vector_type(8)));

// ---------------- squared norms (unscaled f32) ----------------
__global__ __launch_bounds__(256) void sqnorm_kernel(const float* __restrict__ X,
                                                     float* __restrict__ out, int rows) {
    int r = blockIdx.x * 256 + threadIdx.x;
    if (r >= rows) return;
    const float4* p = (const float4*)(X + (size_t)r * D_FEAT);
    float s = 0.f;
    #pragma unroll
    for (int i = 0; i < D_FEAT / 4; ++i) {
        float4 v = p[i];
        s += v.x * v.x + v.y * v.y + v.z * v.z + v.w * v.w;
    }
    out[r] = s;
}

// ---------------- f32 -> scaled f16 (hi,lo) split, K-concatenated ----------------
__global__ __launch_bounds__(128) void split_kernel(const float* __restrict__ X,
                                                    unsigned short* __restrict__ out,
                                                    int isA) {
    int row = blockIdx.x;
    int k   = threadIdx.x;
    float a = X[(size_t)row * D_FEAT + k] * SCALE;
    _Float16 h = (_Float16)a;
    float hf = (float)h;
    _Float16 l = (_Float16)(a - hf);
    unsigned short hu, lu;
    __builtin_memcpy(&hu, &h, 2);
    __builtin_memcpy(&lu, &l, 2);
    size_t b = (size_t)row * KSPLIT;
    out[b + k]              = hu;
    out[b + D_FEAT + k]     = isA ? hu : lu;
    out[b + 2 * D_FEAT + k] = isA ? lu : hu;
}

// ---------------- MFMA distance kernel (gload_lds + dbuf) -> 16-bit keys ----------------
#define BM 128
#define BN 256
#define BKS 32                 // 32 halves = 64 B per row per slab
#define NSLAB (KSPLIT / BKS)   // 12
#define ASLOT (BM * 4)         // 512 16B-slots
#define BSLOT (BN * 4)         // 1024 16B-slots
#define BUFELEM ((ASLOT + BSLOT) * 8)   // u16 elems per buffer (12288 = 24 KB)

static __device__ __forceinline__ half8 lds_read_half8(const unsigned short* p) {
    half8 r;
    __builtin_memcpy(&r, p, 16);
    return r;
}

static __device__ __forceinline__ void gload_lds16(const unsigned short* g, unsigned short* l) {
    __builtin_amdgcn_global_load_lds(
        (const __attribute__((address_space(1))) unsigned int*)g,
        (__attribute__((address_space(3))) unsigned int*)l, 16, 0, 0);
}

// stage one BK=32 slab of A(128 rows) + B(256 rows) into buf via global_load_lds.
// LDS dest is linear in slot = row*4 + c ; GLOBAL source chunk is pre-swizzled
// sc = c ^ ((row>>1)&3) so compute-side ds_read_b128 (same XOR) is conflict-free.
static __device__ __forceinline__ void stage_slab(
        const unsigned short* __restrict__ Asp,
        const unsigned short* __restrict__ Bsp,
        unsigned short* buf, int aRowBase, int bRowBase, int kt, int w, int l) {
    {   // A: 512 slots, one wave-round
        int slot = w * 64 + l;
        int row = slot >> 2, c = slot & 3;
        int sc  = c ^ ((row >> 1) & 3);
        gload_lds16(Asp + (size_t)(aRowBase + row) * KSPLIT + kt + sc * 8,
                    buf + (size_t)(w * 64) * 8);
    }
    #pragma unroll
    for (int r = 0; r < 2; ++r) {   // B: 1024 slots, two wave-rounds
        int slot = r * 512 + w * 64 + l;
        int row = slot >> 2, c = slot & 3;
        int sc  = c ^ ((row >> 1) & 3);
        gload_lds16(Bsp + (size_t)(bRowBase + row) * KSPLIT + kt + sc * 8,
                    buf + ASLOT * 8 + (size_t)(r * 512 + w * 64) * 8);
    }
}

__global__ __launch_bounds__(512, 4) void dist_mfma_kernel(
        const unsigned short* __restrict__ Asp,   // [n][384]
        const unsigned short* __restrict__ Bsp,   // [N][384]
        const float* __restrict__ x2,
        const float* __restrict__ y2,
        unsigned short* __restrict__ keyout,      // row-major [chunk][N]
        int q0, int N, int rowsM) {
    __shared__ __align__(16) unsigned short sh[2 * BUFELEM];   // 48 KB
    unsigned short* bufA = sh;
    unsigned short* bufB = sh + BUFELEM;

    // XCD-aware swizzle: column-major per XCD (contiguous N-band per XCD)
    const int nwg = (N / BN) * rowsM;      // multiple of 8
    const int cpx = nwg >> 3;
    const int bid = blockIdx.x;
    const int swz = (bid & 7) * cpx + (bid >> 3);
    const int col   = swz / rowsM;
    const int mrowi = swz - col * rowsM;
    const int nb = col * BN;
    const int mb = mrowi * BM;

    const int tid  = threadIdx.x;
    const int lane = tid & 63;
    const int w    = tid >> 6;
    const int wr   = w >> 2, wc = w & 3;   // 2 x 4 wave grid, 64x64 per wave

    f32x4 acc[4][4];
    #pragma unroll
    for (int i = 0; i < 4; ++i)
        #pragma unroll
        for (int j = 0; j < 4; ++j)
            acc[i][j] = (f32x4){0.f, 0.f, 0.f, 0.f};

    stage_slab(Asp, Bsp, bufA, q0 + mb, nb, 0, w, lane);

    const int c = lane >> 4;               // K chunk 0..3
    for (int s = 0; s < NSLAB; ++s) {
        __syncthreads();                   // drains stage(s) + compute(s-1) done
        unsigned short* cur = (s & 1) ? bufB : bufA;
        unsigned short* nxt = (s & 1) ? bufA : bufB;
        if (s + 1 < NSLAB)
            stage_slab(Asp, Bsp, nxt, q0 + mb, nb, (s + 1) * BKS, w, lane);  // DMA overlaps MFMA
        const unsigned short* Acur = cur;
        const unsigned short* Bcur = cur + ASLOT * 8;
        half8 af[4], bf[4];
        #pragma unroll
        for (int f = 0; f < 4; ++f) {
            int m  = wr * 64 + f * 16 + (lane & 15);
            af[f] = lds_read_half8(Acur + (size_t)(m * 4 + (c ^ ((m >> 1) & 3))) * 8);
            int nn = wc * 64 + f * 16 + (lane & 15);
            bf[f] = lds_read_half8(Bcur + (size_t)(nn * 4 + (c ^ ((nn >> 1) & 3))) * 8);
        }
        #pragma unroll
        for (int i = 0; i < 4; ++i)
            #pragma unroll
            for (int j = 0; j < 4; ++j)
                acc[i][j] = __builtin_amdgcn_mfma_f32_16x16x32_f16(af[i], bf[j], acc[i][j], 0, 0, 0);
    }

    // ---- epilogue: direct key16 stores (row-major) ----
    float x2v[16];
    #pragma unroll
    for (int fi = 0; fi < 4; ++fi)
        #pragma unroll
        for (int r = 0; r < 4; ++r)
            x2v[fi * 4 + r] = x2[q0 + mb + wr * 64 + fi * 16 + (lane >> 4) * 4 + r];
    #pragma unroll
    for (int fj = 0; fj < 4; ++fj) {
        float yv = y2[nb + wc * 64 + fj * 16 + (lane & 15)];
        #pragma unroll
        for (int fi = 0; fi < 4; ++fi) {
            #pragma unroll
            for (int r = 0; r < 4; ++r) {
                float d = fmaf(-2.0f, acc[fi][fj][r], SCALE2 * (x2v[fi * 4 + r] + yv));
                d = fmaxf(d, 0.0f);
                int m  = mb + wr * 64 + fi * 16 + (lane >> 4) * 4 + r;
                int nn = nb + wc * 64 + fj * 16 + (lane & 15);
                keyout[(size_t)m * N + nn] = (unsigned short)(__float_as_uint(d) >> 15);
            }
        }
    }
}

// ---------------- selection + vote (v6): sample -> gather -> small select ----------------
// 1 block / query. Sample first 1024 keys (i.i.d. across j), pick T = R-th
// smallest sample, gather all keys < T (~1K) into LDS once, then run the
// 3-probe tau search over the small candidate set. Exact f64 tie ranking.
#define SEL_T   1024
#define CAP     8192          // candidate cap (32 KB)
#define TIE_CAP 1024

__global__ __launch_bounds__(SEL_T, 8) void select6_kernel(
        const unsigned short* __restrict__ keys,
        const float* __restrict__ labels,
        const float* __restrict__ Q, const float* __restrict__ Dta,
        int* __restrict__ out, int q0, int N, int n_total, int out_size) {
    __shared__ unsigned int cand[CAP];       // (key16<<16) | j
    __shared__ double       cval[TIE_CAP];
    __shared__ unsigned int ckey[TIE_CAP];   // j | (label<<31)
    __shared__ unsigned int red[2][3][16];
    __shared__ unsigned int tot[2][3];
    __shared__ unsigned int mcnt, votes_sh, tcnt;

    const int tid = threadIdx.x;
    const int qi  = q0 + blockIdx.x;
    const unsigned short* row = keys + (size_t)blockIdx.x * N;

    const uint32_t sv = row[tid];            // sample: first 1024 keys (coalesced)
    if (tid == 0) { votes_sh = 0; tcnt = 0; }

    uint32_t T = 0, total = 0;
    uint32_t R = 16;                         // expected gather ~64*R
    for (int attempt = 0; attempt < 3; ++attempt) {
        // ---- sample select: T = R-th smallest sample ----
        uint32_t lo = 0, hi = 65536;
        #pragma unroll 1
        for (int pass = 0; pass < 8; ++pass) {
            uint32_t qs = (hi - lo) >> 2;
            uint32_t p1 = lo + qs, p2 = p1 + qs, p3 = p2 + qs;
            uint32_t c1 = (sv < p1), c2 = (sv < p2), c3 = (sv < p3);
            #pragma unroll
            for (int off = 32; off > 0; off >>= 1) {
                c1 += __shfl_down(c1, off, 64);
                c2 += __shfl_down(c2, off, 64);
                c3 += __shfl_down(c3, off, 64);
            }
            int bsel = pass & 1;
            if ((tid & 63) == 0) {
                int ww = tid >> 6;
                red[bsel][0][ww] = c1; red[bsel][1][ww] = c2; red[bsel][2][ww] = c3;
            }
            __syncthreads();
            if (tid < 48) {
                int g = tid >> 4, i = tid & 15;
                unsigned int v = red[bsel][g][i];
                v += __shfl_xor(v, 1, 64);
                v += __shfl_xor(v, 2, 64);
                v += __shfl_xor(v, 4, 64);
                v += __shfl_xor(v, 8, 64);
                if (i == 0) tot[bsel][g] = v;
            }
            __syncthreads();
            uint32_t t1 = tot[bsel][0], t2 = tot[bsel][1], t3 = tot[bsel][2];
            if      (t1 >= R) { hi = p1; }
            else if (t2 >= R) { lo = p1; hi = p2; }
            else if (t3 >= R) { lo = p2; hi = p3; }
            else              { lo = p3; }
        }
        T = lo;
        // ---- gather pass: all keys < T into cand[] (exact count in mcnt) ----
        if (tid == 0) mcnt = 0;
        __syncthreads();
        #pragma unroll 1
        for (int r = 0; r < 8; ++r) {
            uint4 v = *(const uint4*)(row + r * 8192 + tid * 8);
            #pragma unroll
            for (int w2 = 0; w2 < 4; ++w2) {
                uint32_t p = (w2 == 0) ? v.x : (w2 == 1) ? v.y : (w2 == 2) ? v.z : v.w;
                #pragma unroll
                for (int h = 0; h < 2; ++h) {
                    uint32_t key = (h == 0) ? (p & 0xFFFFu) : (p >> 16);
                    if (key < T) {
                        uint32_t j = (uint32_t)((r * 1024 + tid) * 8 + w2 * 2 + h);
                        unsigned int e = atomicAdd(&mcnt, 1u);
                        if (e < CAP) cand[e] = (key << 16) | j;
                    }
                }
            }
        }
        __syncthreads();
        total = mcnt;
        if (total >= TOPK && total <= CAP) break;
        R = (attempt == 0) ? 64u : 1023u;
        __syncthreads();     // protect mcnt reset vs stragglers reading total
    }
    const int m = (int)((total < CAP) ? total : CAP);

    // ---- tau search over candidates (counts saturate at >= TOPK above T: ok) ----
    uint32_t lo = 0, hi = 65536, base = 0;
    #pragma unroll 1
    for (int pass = 0; pass < 8; ++pass) {
        uint32_t qs = (hi - lo) >> 2;
        uint32_t p1 = lo + qs, p2 = p1 + qs, p3 = p2 + qs;
        uint32_t c1 = 0, c2 = 0, c3 = 0;
        #pragma unroll
        for (int p = 0; p < 8; ++p) {
            int idx = p * 1024 + tid;
            if (idx < m) {
                uint32_t key = cand[idx] >> 16;
                c1 += (key < p1); c2 += (key < p2); c3 += (key < p3);
            }
        }
        #pragma unroll
        for (int off = 32; off > 0; off >>= 1) {
            c1 += __shfl_down(c1, off, 64);
            c2 += __shfl_down(c2, off, 64);
            c3 += __shfl_down(c3, off, 64);
        }
        int bsel = pass & 1;
        if ((tid & 63) == 0) {
            int ww = tid >> 6;
            red[bsel][0][ww] = c1; red[bsel][1][ww] = c2; red[bsel][2][ww] = c3;
        }
        __syncthreads();
        if (tid < 48) {
            int g = tid >> 4, i = tid & 15;
            unsigned int v = red[bsel][g][i];
            v += __shfl_xor(v, 1, 64);
            v += __shfl_xor(v, 2, 64);
            v += __shfl_xor(v, 4, 64);
            v += __shfl_xor(v, 8, 64);
            if (i == 0) tot[bsel][g] = v;
        }
        __syncthreads();
        uint32_t t1 = tot[bsel][0], t2 = tot[bsel][1], t3 = tot[bsel][2];
        if      (t1 >= TOPK) { hi = p1; }
        else if (t2 >= TOPK) { lo = p1; hi = p2; base = t1; }
        else if (t3 >= TOPK) { lo = p2; hi = p3; base = t2; }
        else                 { lo = p3;          base = t3; }
    }
    const uint32_t tau    = lo;
    const uint32_t t_take = TOPK - base;

    // ---- vote below tau; gather tau-ties with exact f64 distances ----
    uint32_t votes = 0;
    #pragma unroll 1
    for (int p = 0; p < 8; ++p) {
        int idx = p * 1024 + tid;
        if (idx < m) {
            uint32_t u = cand[idx];
            uint32_t key = u >> 16;
            uint32_t j   = u & 0xFFFFu;
            if (key < tau) {
                votes += (labels[j] > 0.5f) ? 1u : 0u;
            } else if (key == tau) {
                unsigned int lab = (labels[j] > 0.5f) ? 0x80000000u : 0u;
                unsigned int e = atomicAdd(&tcnt, 1u);
                if (e < TIE_CAP) {
                    const float* qp = Q   + (size_t)qi * D_FEAT;
                    const float* dp = Dta + (size_t)j  * D_FEAT;
                    double sacc = 0.0;
                    for (int k = 0; k < D_FEAT; ++k) {
                        double df = (double)qp[k] - (double)dp[k];
                        sacc = fma(df, df, sacc);
                    }
                    cval[e] = sacc;
                    ckey[e] = j | lab;
                }
            }
        }
    }
    #pragma unroll
    for (int off = 32; off > 0; off >>= 1)
        votes += __shfl_down(votes, off, 64);
    if ((tid & 63) == 0 && votes) atomicAdd(&votes_sh, votes);
    __syncthreads();

    unsigned int mt = tcnt; if (mt > TIE_CAP) mt = TIE_CAP;
    for (unsigned int e = tid; e < mt; e += SEL_T) {
        double       ve = cval[e];
        unsigned int ke = ckey[e];
        unsigned int ie = ke & 0x7FFFFFFFu;
        unsigned int rank = 0;
        for (unsigned int f = 0; f < mt; ++f) {
            double       vf = cval[f];
            unsigned int jf = ckey[f] & 0x7FFFFFFFu;
            rank += (vf < ve || (vf == ve && jf < ie)) ? 1u : 0u;
        }
        if (rank < t_take && (ke & 0x80000000u)) atomicAdd(&votes_sh, 1u);
    }
    __syncthreads();

    if (tid == 0) {
        unsigned int v1 = votes_sh;
        out[qi] = (v1 > TOPK / 2) ? 1 : 0;          // 64/64 tie -> class 0
        if (qi == 0 && out_size > n_total) out[n_total] = 0;
    }
}

// ---------------- host ----------------
extern "C" void kernel_launch(void* const* d_in, const int* in_sizes, int n_in,
                              void* d_out, int out_size, void* d_ws, size_t ws_size,
                              hipStream_t stream) {
    const float* Q   = (const float*)d_in[0];
    const float* Dta = (const float*)d_in[1];
    const float* L   = (const float*)d_in[2];
    const int n = in_sizes[0] / D_FEAT;    // 2048
    const int N = in_sizes[1] / D_FEAT;    // 65536
    int* out = (int*)d_out;

    char* ws = (char*)d_ws;
    size_t off = 0;
    float* y2 = (float*)(ws + off); off += (((size_t)N * 4) + 255) & ~(size_t)255;
    float* x2 = (float*)(ws + off); off += (((size_t)n * 4) + 255) & ~(size_t)255;
    unsigned short* Asp = (unsigned short*)(ws + off); off += (((size_t)n * KSPLIT * 2) + 255) & ~(size_t)255;
    unsigned short* Bsp = (unsigned short*)(ws + off); off += (((size_t)N * KSPLIT * 2) + 255) & ~(size_t)255;
    unsigned short* keybuf = (unsigned short*)(ws + off);
    size_t avail = (ws_size > off) ? (ws_size - off) : 0;

    long maxQ = (long)(avail / ((size_t)N * 2));
    int chunkQ;
    if (maxQ >= n) chunkQ = n;
    else { chunkQ = (int)((maxQ / BM) * BM); if (chunkQ < BM) chunkQ = BM; }

    sqnorm_kernel<<<dim3((N + 255) / 256), dim3(256), 0, stream>>>(Dta, y2, N);
    sqnorm_kernel<<<dim3((n + 255) / 256), dim3(256), 0, stream>>>(Q, x2, n);
    split_kernel<<<dim3(n), dim3(128), 0, stream>>>(Q, Asp, 1);
    split_kernel<<<dim3(N), dim3(128), 0, stream>>>(Dta, Bsp, 0);

    for (int q0 = 0; q0 < n; q0 += chunkQ) {
        int q = n - q0; if (q > chunkQ) q = chunkQ;
        int rowsM = q / BM;
        int nwg = (N / BN) * rowsM;
        dist_mfma_kernel<<<dim3(nwg), dim3(512), 0, stream>>>(Asp, Bsp, x2, y2, keybuf, q0, N, rowsM);
        select6_kernel<<<dim3(q), dim3(SEL_T), 0, stream>>>(keybuf, L, Q, Dta, out, q0, N, n, out_size);
    }
}

// Round 10
// 352.112 us; speedup vs baseline: 1.7184x; 1.2310x over previous
//
#include <hip/hip_runtime.h>
#include <stdint.h>

#define D_FEAT   128
#define TOPK     128
#define KSPLIT   384           // 3 x 128 (h|h|l) . (h|l|h)
#define SCALE    4096.0f
#define SCALE2   16777216.0f   // SCALE^2 (2^24, exact)
#define SEL_CAP  8192          // per-query candidate capacity
#define SAMPLE_N 1024
#define SAMPLE_R 24

typedef float    f32x4 __attribute__((ext_vector_type(4)));
typedef _Float16 half8 __attribute__((ext_vector_type(8)));

// ---------------- squared norms ----------------
__global__ __launch_bounds__(256) void sqnorm_kernel(const float* __restrict__ X,
                                                     float* __restrict__ out, int rows) {
    int r = blockIdx.x * 256 + threadIdx.x;
    if (r >= rows) return;
    const float4* p = (const float4*)(X + (size_t)r * D_FEAT);
    float s = 0.f;
    #pragma unroll
    for (int i = 0; i < D_FEAT / 4; ++i) {
        float4 v = p[i];
        s += v.x * v.x + v.y * v.y + v.z * v.z + v.w * v.w;
    }
    out[r] = s;
}

// ---------------- f32 -> scaled f16 (hi,lo) split ----------------
__global__ __launch_bounds__(128) void split_kernel(const float* __restrict__ X,
                                                    unsigned short* __restrict__ out,
                                                    int isA) {
    int row = blockIdx.x;
    int k   = threadIdx.x;
    float a = X[(size_t)row * D_FEAT + k] * SCALE;
    _Float16 h = (_Float16)a;
    float hf = (float)h;
    _Float16 l = (_Float16)(a - hf);
    unsigned short hu, lu;
    __builtin_memcpy(&hu, &h, 2);
    __builtin_memcpy(&lu, &l, 2);
    size_t b = (size_t)row * KSPLIT;
    out[b + k]              = hu;
    out[b + D_FEAT + k]     = isA ? hu : lu;
    out[b + 2 * D_FEAT + k] = isA ? lu : hu;
}

// ---------------- MFMA distance kernel ----------------
// MODE 0: write key16s to keyout (prepass on sample columns)
// MODE 1: filter vs Tq[row], append candidates (key16<<16 | j) to candbuf
#define BM 128
#define BN 256
#define BKS 32
#define NSLAB (KSPLIT / BKS)   // 12
#define ASLOT (BM * 4)
#define BSLOT (BN * 4)
#define BUFELEM ((ASLOT + BSLOT) * 8)   // u16 per buffer (24 KB)

static __device__ __forceinline__ half8 lds_read_half8(const unsigned short* p) {
    half8 r;
    __builtin_memcpy(&r, p, 16);
    return r;
}

static __device__ __forceinline__ void gload_lds16(const unsigned short* g, unsigned short* l) {
    __builtin_amdgcn_global_load_lds(
        (const __attribute__((address_space(1))) unsigned int*)g,
        (__attribute__((address_space(3))) unsigned int*)l, 16, 0, 0);
}

static __device__ __forceinline__ void stage_slab(
        const unsigned short* __restrict__ Asp,
        const unsigned short* __restrict__ Bsp,
        unsigned short* buf, int aRowBase, int bRowBase, int kt, int w, int l) {
    {
        int slot = w * 64 + l;
        int row = slot >> 2, c = slot & 3;
        int sc  = c ^ ((row >> 1) & 3);
        gload_lds16(Asp + (size_t)(aRowBase + row) * KSPLIT + kt + sc * 8,
                    buf + (size_t)(w * 64) * 8);
    }
    #pragma unroll
    for (int r = 0; r < 2; ++r) {
        int slot = r * 512 + w * 64 + l;
        int row = slot >> 2, c = slot & 3;
        int sc  = c ^ ((row >> 1) & 3);
        gload_lds16(Bsp + (size_t)(bRowBase + row) * KSPLIT + kt + sc * 8,
                    buf + ASLOT * 8 + (size_t)(r * 512 + w * 64) * 8);
    }
}

template<int MODE>
__global__ __launch_bounds__(512, 4) void dist_mfma_kernel(
        const unsigned short* __restrict__ Asp,   // [n][384]
        const unsigned short* __restrict__ Bsp,   // [N][384]
        const float* __restrict__ x2,
        const float* __restrict__ y2,
        unsigned short* __restrict__ keyout,      // MODE 0: [n][N]
        const unsigned int* __restrict__ Tq,      // MODE 1
        unsigned int* __restrict__ cnt,           // MODE 1
        unsigned int* __restrict__ candbuf,       // MODE 1
        int N, int rowsM) {
    __shared__ __align__(16) unsigned char shraw[2 * BUFELEM * 2];   // 48 KB
    unsigned short* bufA = (unsigned short*)shraw;
    unsigned short* bufB = bufA + BUFELEM;

    const int nwg = (N / BN) * rowsM;
    const int cpx = nwg >> 3;
    const int bid = blockIdx.x;
    const int swz = (bid & 7) * cpx + (bid >> 3);
    const int col   = swz / rowsM;
    const int mrowi = swz - col * rowsM;
    const int nb = col * BN;
    const int mb = mrowi * BM;

    const int tid  = threadIdx.x;
    const int lane = tid & 63;
    const int w    = tid >> 6;
    const int wr   = w >> 2, wc = w & 3;

    f32x4 acc[4][4];
    #pragma unroll
    for (int i = 0; i < 4; ++i)
        #pragma unroll
        for (int j = 0; j < 4; ++j)
            acc[i][j] = (f32x4){0.f, 0.f, 0.f, 0.f};

    stage_slab(Asp, Bsp, bufA, mb, nb, 0, w, lane);

    const int c = lane >> 4;
    for (int s = 0; s < NSLAB; ++s) {
        __syncthreads();
        unsigned short* cur = (s & 1) ? bufB : bufA;
        unsigned short* nxt = (s & 1) ? bufA : bufB;
        if (s + 1 < NSLAB)
            stage_slab(Asp, Bsp, nxt, mb, nb, (s + 1) * BKS, w, lane);
        const unsigned short* Acur = cur;
        const unsigned short* Bcur = cur + ASLOT * 8;
        half8 af[4], bf[4];
        #pragma unroll
        for (int f = 0; f < 4; ++f) {
            int m  = wr * 64 + f * 16 + (lane & 15);
            af[f] = lds_read_half8(Acur + (size_t)(m * 4 + (c ^ ((m >> 1) & 3))) * 8);
            int nn = wc * 64 + f * 16 + (lane & 15);
            bf[f] = lds_read_half8(Bcur + (size_t)(nn * 4 + (c ^ ((nn >> 1) & 3))) * 8);
        }
        #pragma unroll
        for (int i = 0; i < 4; ++i)
            #pragma unroll
            for (int j = 0; j < 4; ++j)
                acc[i][j] = __builtin_amdgcn_mfma_f32_16x16x32_f16(af[i], bf[j], acc[i][j], 0, 0, 0);
    }

    __syncthreads();    // all LDS reads done before epilogue reuse

    float x2v[16];
    unsigned int Trow[16];
    #pragma unroll
    for (int fi = 0; fi < 4; ++fi)
        #pragma unroll
        for (int r = 0; r < 4; ++r) {
            int ml = wr * 64 + fi * 16 + (lane >> 4) * 4 + r;
            x2v[fi * 4 + r] = x2[mb + ml];
            if (MODE == 1) Trow[fi * 4 + r] = Tq[mb + ml];
        }

    if (MODE == 0) {
        #pragma unroll
        for (int fj = 0; fj < 4; ++fj) {
            float yv = y2[nb + wc * 64 + fj * 16 + (lane & 15)];
            #pragma unroll
            for (int fi = 0; fi < 4; ++fi) {
                #pragma unroll
                for (int r = 0; r < 4; ++r) {
                    float d = fmaf(-2.0f, acc[fi][fj][r], SCALE2 * (x2v[fi * 4 + r] + yv));
                    d = fmaxf(d, 0.0f);
                    int m  = mb + wr * 64 + fi * 16 + (lane >> 4) * 4 + r;
                    int nn = nb + wc * 64 + fj * 16 + (lane & 15);
                    keyout[(size_t)m * N + nn] = (unsigned short)(__float_as_uint(d) >> 15);
                }
            }
        }
    } else {
        // per-row LDS hit lists -> one global atomic per (row, block)
        unsigned int* rowcnt  = (unsigned int*)shraw;          // 128
        unsigned int* slots   = rowcnt + 128;                  // 128*32
        unsigned int* rowbase = slots + 128 * 32;              // 128
        for (int i = tid; i < 128; i += 512) rowcnt[i] = 0;
        __syncthreads();
        #pragma unroll
        for (int fj = 0; fj < 4; ++fj) {
            float yv = y2[nb + wc * 64 + fj * 16 + (lane & 15)];
            #pragma unroll
            for (int fi = 0; fi < 4; ++fi) {
                #pragma unroll
                for (int r = 0; r < 4; ++r) {
                    float d = fmaf(-2.0f, acc[fi][fj][r], SCALE2 * (x2v[fi * 4 + r] + yv));
                    d = fmaxf(d, 0.0f);
                    unsigned int key = __float_as_uint(d) >> 15;
                    if (key < Trow[fi * 4 + r]) {
                        int ml = wr * 64 + fi * 16 + (lane >> 4) * 4 + r;
                        int cl = wc * 64 + fj * 16 + (lane & 15);
                        unsigned int p = atomicAdd(&rowcnt[ml], 1u);
                        if (p < 32) {
                            slots[ml * 32 + p] = (key << 16) | (unsigned int)cl;
                        } else {   // rare spill: direct global append
                            unsigned int b = atomicAdd(&cnt[mb + ml], 1u);
                            if (b < SEL_CAP)
                                candbuf[(size_t)(mb + ml) * SEL_CAP + b] =
                                    (key << 16) | (unsigned int)(nb + cl);
                        }
                    }
                }
            }
        }
        __syncthreads();
        int ml2 = tid >> 2;                  // 512 threads -> 4 per row
        unsigned int cc = rowcnt[ml2]; if (cc > 32) cc = 32;
        if ((tid & 3) == 0) rowbase[ml2] = atomicAdd(&cnt[mb + ml2], cc);
        __syncthreads();
        unsigned int b0 = rowbase[ml2];
        for (unsigned int i = tid & 3; i < cc; i += 4) {
            unsigned int e = slots[ml2 * 32 + i];
            unsigned int dst = b0 + i;
            if (dst < SEL_CAP)
                candbuf[(size_t)(mb + ml2) * SEL_CAP + dst] =
                    (e & 0xFFFF0000u) | (unsigned int)(nb + (e & 0xFFu));
        }
    }
}

// ---------------- per-query threshold from sample keys ----------------
// T_q = (SAMPLE_R-th smallest of 1024 sample keys) + 1, via 2-level histogram.
__global__ __launch_bounds__(256) void tsel_kernel(const unsigned short* __restrict__ skey,
                                                   unsigned int* __restrict__ Tq) {
    __shared__ unsigned int hist[256];
    __shared__ unsigned int binsel, cumsel, losel;
    const int tid = threadIdx.x;
    const int q   = blockIdx.x;
    uint2 v = ((const uint2*)(skey + (size_t)q * SAMPLE_N))[tid];   // 4 keys
    unsigned int k0 = v.x & 0xFFFFu, k1 = v.x >> 16;
    unsigned int k2 = v.y & 0xFFFFu, k3 = v.y >> 16;

    // level 0: high byte
    hist[tid] = 0;
    __syncthreads();
    atomicAdd(&hist[k0 >> 8], 1u); atomicAdd(&hist[k1 >> 8], 1u);
    atomicAdd(&hist[k2 >> 8], 1u); atomicAdd(&hist[k3 >> 8], 1u);
    __syncthreads();
    if (tid == 0) {
        unsigned int cum = 0;
        for (int b = 0; b < 256; ++b) {
            unsigned int h = hist[b];
            if (cum + h >= SAMPLE_R) { binsel = (unsigned int)b; cumsel = cum; break; }
            cum += h;
        }
    }
    __syncthreads();
    unsigned int bsel = binsel, need = SAMPLE_R - cumsel;
    // level 1: low byte within selected bin
    hist[tid] = 0;
    __syncthreads();
    if ((k0 >> 8) == bsel) atomicAdd(&hist[k0 & 0xFFu], 1u);
    if ((k1 >> 8) == bsel) atomicAdd(&hist[k1 & 0xFFu], 1u);
    if ((k2 >> 8) == bsel) atomicAdd(&hist[k2 & 0xFFu], 1u);
    if ((k3 >> 8) == bsel) atomicAdd(&hist[k3 & 0xFFu], 1u);
    __syncthreads();
    if (tid == 0) {
        unsigned int cum = 0;
        for (int b = 0; b < 256; ++b) {
            cum += hist[b];
            if (cum >= need) { losel = (unsigned int)b; break; }
        }
        Tq[q] = ((bsel << 8) | losel) + 1u;
    }
}

// ---------------- selection + vote over candidate lists ----------------
#define SEL_T   1024
#define TIE_CAP 1024

__global__ __launch_bounds__(SEL_T) void select7_kernel(
        const unsigned int* __restrict__ cnt,
        const unsigned int* __restrict__ candbuf,
        const float* __restrict__ labels,
        const float* __restrict__ Q, const float* __restrict__ Dta,
        int* __restrict__ out, int n_total, int out_size) {
    __shared__ unsigned int cand[SEL_CAP];   // 32 KB
    __shared__ double       cval[TIE_CAP];   // 8 KB
    __shared__ unsigned int ckey[TIE_CAP];   // 4 KB
    __shared__ unsigned int red[2][3][16];
    __shared__ unsigned int tot[2][3];
    __shared__ unsigned int votes_sh, tcnt;

    const int tid = threadIdx.x;
    const int q   = blockIdx.x;

    unsigned int mraw = cnt[q];
    const int m = (int)(mraw < SEL_CAP ? mraw : SEL_CAP);
    for (int i = tid; i < m; i += SEL_T) cand[i] = candbuf[(size_t)q * SEL_CAP + i];
    if (tid == 0) { votes_sh = 0; tcnt = 0; }
    __syncthreads();

    // 8 passes x 3 probes: tau = key16 of the 128th smallest (complete below T)
    uint32_t lo = 0, hi = 65536, base = 0;
    #pragma unroll 1
    for (int pass = 0; pass < 8; ++pass) {
        uint32_t qs = (hi - lo) >> 2;
        uint32_t p1 = lo + qs, p2 = p1 + qs, p3 = p2 + qs;
        uint32_t c1 = 0, c2 = 0, c3 = 0;
        #pragma unroll
        for (int p = 0; p < 8; ++p) {
            int idx = p * 1024 + tid;
            if (idx < m) {
                uint32_t key = cand[idx] >> 16;
                c1 += (key < p1); c2 += (key < p2); c3 += (key < p3);
            }
        }
        #pragma unroll
        for (int off = 32; off > 0; off >>= 1) {
            c1 += __shfl_down(c1, off, 64);
            c2 += __shfl_down(c2, off, 64);
            c3 += __shfl_down(c3, off, 64);
        }
        int bsel = pass & 1;
        if ((tid & 63) == 0) {
            int ww = tid >> 6;
            red[bsel][0][ww] = c1; red[bsel][1][ww] = c2; red[bsel][2][ww] = c3;
        }
        __syncthreads();
        if (tid < 48) {
            int g = tid >> 4, i = tid & 15;
            unsigned int v = red[bsel][g][i];
            v += __shfl_xor(v, 1, 64);
            v += __shfl_xor(v, 2, 64);
            v += __shfl_xor(v, 4, 64);
            v += __shfl_xor(v, 8, 64);
            if (i == 0) tot[bsel][g] = v;
        }
        __syncthreads();
        uint32_t t1 = tot[bsel][0], t2 = tot[bsel][1], t3 = tot[bsel][2];
        if      (t1 >= TOPK) { hi = p1; }
        else if (t2 >= TOPK) { lo = p1; hi = p2; base = t1; }
        else if (t3 >= TOPK) { lo = p2; hi = p3; base = t2; }
        else                 { lo = p3;          base = t3; }
    }
    const uint32_t tau    = lo;
    const uint32_t t_take = TOPK - base;

    // vote below tau; gather tau-ties with exact f64 distances
    uint32_t votes = 0;
    #pragma unroll 1
    for (int p = 0; p < 8; ++p) {
        int idx = p * 1024 + tid;
        if (idx < m) {
            uint32_t u = cand[idx];
            uint32_t key = u >> 16;
            uint32_t j   = u & 0xFFFFu;
            if (key < tau) {
                votes += (labels[j] > 0.5f) ? 1u : 0u;
            } else if (key == tau) {
                unsigned int lab = (labels[j] > 0.5f) ? 0x80000000u : 0u;
                unsigned int e = atomicAdd(&tcnt, 1u);
                if (e < TIE_CAP) {
                    const float* qp = Q   + (size_t)q * D_FEAT;
                    const float* dp = Dta + (size_t)j * D_FEAT;
                    double sacc = 0.0;
                    for (int k = 0; k < D_FEAT; ++k) {
                        double df = (double)qp[k] - (double)dp[k];
                        sacc = fma(df, df, sacc);
                    }
                    cval[e] = sacc;
                    ckey[e] = j | lab;
                }
            }
        }
    }
    #pragma unroll
    for (int off = 32; off > 0; off >>= 1)
        votes += __shfl_down(votes, off, 64);
    if ((tid & 63) == 0 && votes) atomicAdd(&votes_sh, votes);
    __syncthreads();

    unsigned int mt = tcnt; if (mt > TIE_CAP) mt = TIE_CAP;
    for (unsigned int e = tid; e < mt; e += SEL_T) {
        double       ve = cval[e];
        unsigned int ke = ckey[e];
        unsigned int ie = ke & 0x7FFFFFFFu;
        unsigned int rank = 0;
        for (unsigned int f = 0; f < mt; ++f) {
            double       vf = cval[f];
            unsigned int jf = ckey[f] & 0x7FFFFFFFu;
            rank += (vf < ve || (vf == ve && jf < ie)) ? 1u : 0u;
        }
        if (rank < t_take && (ke & 0x80000000u)) atomicAdd(&votes_sh, 1u);
    }
    __syncthreads();

    if (tid == 0) {
        out[q] = (votes_sh > TOPK / 2) ? 1 : 0;     // 64/64 tie -> class 0
        if (q == 0 && out_size > n_total) out[n_total] = 0;
    }
}

// ---------------- host ----------------
extern "C" void kernel_launch(void* const* d_in, const int* in_sizes, int n_in,
                              void* d_out, int out_size, void* d_ws, size_t ws_size,
                              hipStream_t stream) {
    const float* Q   = (const float*)d_in[0];
    const float* Dta = (const float*)d_in[1];
    const float* L   = (const float*)d_in[2];
    const int n = in_sizes[0] / D_FEAT;    // 2048
    const int N = in_sizes[1] / D_FEAT;    // 65536
    int* out = (int*)d_out;

    char* ws = (char*)d_ws;
    size_t off = 0;
    float* y2 = (float*)(ws + off);          off += (((size_t)N * 4) + 255) & ~(size_t)255;
    float* x2 = (float*)(ws + off);          off += (((size_t)n * 4) + 255) & ~(size_t)255;
    unsigned short* Asp = (unsigned short*)(ws + off); off += (((size_t)n * KSPLIT * 2) + 255) & ~(size_t)255;
    unsigned short* Bsp = (unsigned short*)(ws + off); off += (((size_t)N * KSPLIT * 2) + 255) & ~(size_t)255;
    unsigned short* skey = (unsigned short*)(ws + off); off += (((size_t)n * SAMPLE_N * 2) + 255) & ~(size_t)255;
    unsigned int* Tq  = (unsigned int*)(ws + off);    off += (((size_t)n * 4) + 255) & ~(size_t)255;
    unsigned int* cnt = (unsigned int*)(ws + off);    off += (((size_t)n * 4) + 255) & ~(size_t)255;
    unsigned int* candbuf = (unsigned int*)(ws + off);   // n * SEL_CAP * 4 = 64 MB

    hipMemsetAsync(cnt, 0, (size_t)n * 4, stream);

    sqnorm_kernel<<<dim3((N + 255) / 256), dim3(256), 0, stream>>>(Dta, y2, N);
    sqnorm_kernel<<<dim3((n + 255) / 256), dim3(256), 0, stream>>>(Q, x2, n);
    split_kernel<<<dim3(n), dim3(128), 0, stream>>>(Q, Asp, 1);
    split_kernel<<<dim3(N), dim3(128), 0, stream>>>(Dta, Bsp, 0);

    const int rowsM = n / BM;                         // 16
    // prepass: keys vs first SAMPLE_N data points
    dist_mfma_kernel<0><<<dim3((SAMPLE_N / BN) * rowsM), dim3(512), 0, stream>>>(
        Asp, Bsp, x2, y2, skey, nullptr, nullptr, nullptr, SAMPLE_N, rowsM);
    tsel_kernel<<<dim3(n), dim3(256), 0, stream>>>(skey, Tq);
    // main: filtered candidate append, full N
    dist_mfma_kernel<1><<<dim3((N / BN) * rowsM), dim3(512), 0, stream>>>(
        Asp, Bsp, x2, y2, nullptr, Tq, cnt, candbuf, N, rowsM);
    select7_kernel<<<dim3(n), dim3(SEL_T), 0, stream>>>(cnt, candbuf, L, Q, Dta, out, n, out_size);
}

// Round 11
// 348.520 us; speedup vs baseline: 1.7361x; 1.0103x over previous
//
#include <hip/hip_runtime.h>
#include <stdint.h>

#define D_FEAT   128
#define TOPK     128
#define KSPLIT   384           // 3 x 128 (h|h|l) . (h|l|h)
#define SCALE    4096.0f
#define SCALE2   16777216.0f   // SCALE^2 (2^24, exact)
#define SEL_CAP  8192          // per-query candidate capacity
#define SAMPLE_N 1024
#define SAMPLE_R 24

typedef float    f32x4 __attribute__((ext_vector_type(4)));
typedef _Float16 half8 __attribute__((ext_vector_type(8)));

// ---------------- squared norms ----------------
__global__ __launch_bounds__(256) void sqnorm_kernel(const float* __restrict__ X,
                                                     float* __restrict__ out, int rows) {
    int r = blockIdx.x * 256 + threadIdx.x;
    if (r >= rows) return;
    const float4* p = (const float4*)(X + (size_t)r * D_FEAT);
    float s = 0.f;
    #pragma unroll
    for (int i = 0; i < D_FEAT / 4; ++i) {
        float4 v = p[i];
        s += v.x * v.x + v.y * v.y + v.z * v.z + v.w * v.w;
    }
    out[r] = s;
}

// ---------------- f32 -> scaled f16 (hi,lo) split (grid-stride) ----------------
__global__ __launch_bounds__(256) void split_kernel(const float* __restrict__ X,
                                                    unsigned short* __restrict__ out,
                                                    int isA, int total) {     // total = rows*128
    for (int idx = blockIdx.x * 256 + threadIdx.x; idx < total; idx += gridDim.x * 256) {
        int row = idx >> 7;
        int k   = idx & 127;
        float a = X[idx] * SCALE;
        _Float16 h = (_Float16)a;
        float hf = (float)h;
        _Float16 l = (_Float16)(a - hf);
        unsigned short hu, lu;
        __builtin_memcpy(&hu, &h, 2);
        __builtin_memcpy(&lu, &l, 2);
        size_t b = (size_t)row * KSPLIT;
        out[b + k]              = hu;
        out[b + D_FEAT + k]     = isA ? hu : lu;
        out[b + 2 * D_FEAT + k] = isA ? lu : hu;
    }
}

// ---------------- MFMA distance kernel (3-buf pipelined, counted vmcnt) ----------------
// MODE 0: write key16s to keyout (prepass on sample columns)
// MODE 1: filter vs Tq[row], append candidates (key16<<16 | j) to candbuf
#define BM 128
#define BN 256
#define BKS 32
#define NSLAB (KSPLIT / BKS)   // 12
#define ASLOT (BM * 4)
#define BSLOT (BN * 4)
#define BUFELEM ((ASLOT + BSLOT) * 8)   // u16 per buffer (24 KB)

static __device__ __forceinline__ half8 lds_read_half8(const unsigned short* p) {
    half8 r;
    __builtin_memcpy(&r, p, 16);
    return r;
}

static __device__ __forceinline__ void gload_lds16(const unsigned short* g, unsigned short* l) {
    __builtin_amdgcn_global_load_lds(
        (const __attribute__((address_space(1))) unsigned int*)g,
        (__attribute__((address_space(3))) unsigned int*)l, 16, 0, 0);
}

// stage one BK=32 slab: exactly 3 gload_lds per thread (vmcnt +3 per wave).
static __device__ __forceinline__ void stage_slab(
        const unsigned short* __restrict__ Asp,
        const unsigned short* __restrict__ Bsp,
        unsigned short* buf, int aRowBase, int bRowBase, int kt, int w, int l) {
    {
        int slot = w * 64 + l;
        int row = slot >> 2, c = slot & 3;
        int sc  = c ^ ((row >> 1) & 3);
        gload_lds16(Asp + (size_t)(aRowBase + row) * KSPLIT + kt + sc * 8,
                    buf + (size_t)(w * 64) * 8);
    }
    #pragma unroll
    for (int r = 0; r < 2; ++r) {
        int slot = r * 512 + w * 64 + l;
        int row = slot >> 2, c = slot & 3;
        int sc  = c ^ ((row >> 1) & 3);
        gload_lds16(Bsp + (size_t)(bRowBase + row) * KSPLIT + kt + sc * 8,
                    buf + ASLOT * 8 + (size_t)(r * 512 + w * 64) * 8);
    }
}

template<int MODE>
__global__ __launch_bounds__(512, 4) void dist_mfma_kernel(
        const unsigned short* __restrict__ Asp,   // [n][384]
        const unsigned short* __restrict__ Bsp,   // [N][384]
        const float* __restrict__ x2,
        const float* __restrict__ y2,
        unsigned short* __restrict__ keyout,      // MODE 0: [n][N]
        const unsigned int* __restrict__ Tq,      // MODE 1
        unsigned int* __restrict__ cnt,           // MODE 1
        unsigned int* __restrict__ candbuf,       // MODE 1
        int N, int rowsM) {
    __shared__ __align__(16) unsigned short sh[3 * BUFELEM];   // 72 KB
    unsigned short* b0 = sh;
    unsigned short* b1 = sh + BUFELEM;
    unsigned short* b2 = sh + 2 * BUFELEM;

    const int nwg = (N / BN) * rowsM;
    const int cpx = nwg >> 3;
    const int bid = blockIdx.x;
    const int swz = (bid & 7) * cpx + (bid >> 3);
    const int col   = swz / rowsM;
    const int mrowi = swz - col * rowsM;
    const int nb = col * BN;
    const int mb = mrowi * BM;

    const int tid  = threadIdx.x;
    const int lane = tid & 63;
    const int w    = tid >> 6;
    const int wr   = w >> 2, wc = w & 3;

    f32x4 acc[4][4];
    #pragma unroll
    for (int i = 0; i < 4; ++i)
        #pragma unroll
        for (int j = 0; j < 4; ++j)
            acc[i][j] = (f32x4){0.f, 0.f, 0.f, 0.f};

    // prologue: 2 slabs in flight
    stage_slab(Asp, Bsp, b0, mb, nb, 0, w, lane);
    stage_slab(Asp, Bsp, b1, mb, nb, BKS, w, lane);

    unsigned short* cur = b0;
    unsigned short* nx1 = b1;
    unsigned short* nx2 = b2;

    const int c = lane >> 4;
    #pragma unroll
    for (int s = 0; s < NSLAB; ++s) {
        // wait only current slab's 3 DMA ops; next slab's stay in flight
        if (s < NSLAB - 1) asm volatile("s_waitcnt vmcnt(3)" ::: "memory");
        else               asm volatile("s_waitcnt vmcnt(0)" ::: "memory");
        __builtin_amdgcn_s_barrier();
        asm volatile("" ::: "memory");
        if (s + 2 < NSLAB)
            stage_slab(Asp, Bsp, nx2, mb, nb, (s + 2) * BKS, w, lane);   // overlaps MFMA

        const unsigned short* Acur = cur;
        const unsigned short* Bcur = cur + ASLOT * 8;
        half8 af[4], bf[4];
        #pragma unroll
        for (int f = 0; f < 4; ++f) {
            int m  = wr * 64 + f * 16 + (lane & 15);
            af[f] = lds_read_half8(Acur + (size_t)(m * 4 + (c ^ ((m >> 1) & 3))) * 8);
            int nn = wc * 64 + f * 16 + (lane & 15);
            bf[f] = lds_read_half8(Bcur + (size_t)(nn * 4 + (c ^ ((nn >> 1) & 3))) * 8);
        }
        __builtin_amdgcn_s_setprio(1);
        #pragma unroll
        for (int i = 0; i < 4; ++i)
            #pragma unroll
            for (int j = 0; j < 4; ++j)
                acc[i][j] = __builtin_amdgcn_mfma_f32_16x16x32_f16(af[i], bf[j], acc[i][j], 0, 0, 0);
        __builtin_amdgcn_s_setprio(0);

        unsigned short* t = cur; cur = nx1; nx1 = nx2; nx2 = t;
    }

    __syncthreads();    // all LDS reads done before epilogue reuse

    float x2v[16];
    unsigned int Trow[16];
    #pragma unroll
    for (int fi = 0; fi < 4; ++fi)
        #pragma unroll
        for (int r = 0; r < 4; ++r) {
            int ml = wr * 64 + fi * 16 + (lane >> 4) * 4 + r;
            x2v[fi * 4 + r] = x2[mb + ml];
            if (MODE == 1) Trow[fi * 4 + r] = Tq[mb + ml];
        }

    if (MODE == 0) {
        #pragma unroll
        for (int fj = 0; fj < 4; ++fj) {
            float yv = y2[nb + wc * 64 + fj * 16 + (lane & 15)];
            #pragma unroll
            for (int fi = 0; fi < 4; ++fi) {
                #pragma unroll
                for (int r = 0; r < 4; ++r) {
                    float d = fmaf(-2.0f, acc[fi][fj][r], SCALE2 * (x2v[fi * 4 + r] + yv));
                    d = fmaxf(d, 0.0f);
                    int m  = mb + wr * 64 + fi * 16 + (lane >> 4) * 4 + r;
                    int nn = nb + wc * 64 + fj * 16 + (lane & 15);
                    keyout[(size_t)m * N + nn] = (unsigned short)(__float_as_uint(d) >> 15);
                }
            }
        }
    } else {
        // per-row LDS hit lists -> one global atomic per (row, block)
        unsigned int* rowcnt  = (unsigned int*)sh;             // 128
        unsigned int* slots   = rowcnt + 128;                  // 128*32
        unsigned int* rowbase = slots + 128 * 32;              // 128
        for (int i = tid; i < 128; i += 512) rowcnt[i] = 0;
        __syncthreads();
        #pragma unroll
        for (int fj = 0; fj < 4; ++fj) {
            float yv = y2[nb + wc * 64 + fj * 16 + (lane & 15)];
            #pragma unroll
            for (int fi = 0; fi < 4; ++fi) {
                #pragma unroll
                for (int r = 0; r < 4; ++r) {
                    float d = fmaf(-2.0f, acc[fi][fj][r], SCALE2 * (x2v[fi * 4 + r] + yv));
                    d = fmaxf(d, 0.0f);
                    unsigned int key = __float_as_uint(d) >> 15;
                    if (key < Trow[fi * 4 + r]) {
                        int ml = wr * 64 + fi * 16 + (lane >> 4) * 4 + r;
                        int cl = wc * 64 + fj * 16 + (lane & 15);
                        unsigned int p = atomicAdd(&rowcnt[ml], 1u);
                        if (p < 32) {
                            slots[ml * 32 + p] = (key << 16) | (unsigned int)cl;
                        } else {   // rare spill: direct global append
                            unsigned int b = atomicAdd(&cnt[mb + ml], 1u);
                            if (b < SEL_CAP)
                                candbuf[(size_t)(mb + ml) * SEL_CAP + b] =
                                    (key << 16) | (unsigned int)(nb + cl);
                        }
                    }
                }
            }
        }
        __syncthreads();
        int ml2 = tid >> 2;                  // 512 threads -> 4 per row
        unsigned int cc = rowcnt[ml2]; if (cc > 32) cc = 32;
        if ((tid & 3) == 0) rowbase[ml2] = atomicAdd(&cnt[mb + ml2], cc);
        __syncthreads();
        unsigned int bse = rowbase[ml2];
        for (unsigned int i = tid & 3; i < cc; i += 4) {
            unsigned int e = slots[ml2 * 32 + i];
            unsigned int dst = bse + i;
            if (dst < SEL_CAP)
                candbuf[(size_t)(mb + ml2) * SEL_CAP + dst] =
                    (e & 0xFFFF0000u) | (unsigned int)(nb + (e & 0xFFu));
        }
    }
}

// ---------------- per-query threshold from sample keys ----------------
__global__ __launch_bounds__(256) void tsel_kernel(const unsigned short* __restrict__ skey,
                                                   unsigned int* __restrict__ Tq) {
    __shared__ unsigned int hist[256];
    __shared__ unsigned int binsel, cumsel, losel;
    const int tid = threadIdx.x;
    const int q   = blockIdx.x;
    uint2 v = ((const uint2*)(skey + (size_t)q * SAMPLE_N))[tid];   // 4 keys
    unsigned int k0 = v.x & 0xFFFFu, k1 = v.x >> 16;
    unsigned int k2 = v.y & 0xFFFFu, k3 = v.y >> 16;

    hist[tid] = 0;
    __syncthreads();
    atomicAdd(&hist[k0 >> 8], 1u); atomicAdd(&hist[k1 >> 8], 1u);
    atomicAdd(&hist[k2 >> 8], 1u); atomicAdd(&hist[k3 >> 8], 1u);
    __syncthreads();
    if (tid == 0) {
        unsigned int cum = 0;
        for (int b = 0; b < 256; ++b) {
            unsigned int h = hist[b];
            if (cum + h >= SAMPLE_R) { binsel = (unsigned int)b; cumsel = cum; break; }
            cum += h;
        }
    }
    __syncthreads();
    unsigned int bsel = binsel, need = SAMPLE_R - cumsel;
    hist[tid] = 0;
    __syncthreads();
    if ((k0 >> 8) == bsel) atomicAdd(&hist[k0 & 0xFFu], 1u);
    if ((k1 >> 8) == bsel) atomicAdd(&hist[k1 & 0xFFu], 1u);
    if ((k2 >> 8) == bsel) atomicAdd(&hist[k2 & 0xFFu], 1u);
    if ((k3 >> 8) == bsel) atomicAdd(&hist[k3 & 0xFFu], 1u);
    __syncthreads();
    if (tid == 0) {
        unsigned int cum = 0;
        for (int b = 0; b < 256; ++b) {
            cum += hist[b];
            if (cum >= need) { losel = (unsigned int)b; break; }
        }
        Tq[q] = ((bsel << 8) | losel) + 1u;
    }
}

// ---------------- selection + vote over candidate lists ----------------
#define SEL_T   1024
#define TIE_CAP 1024

__global__ __launch_bounds__(SEL_T) void select7_kernel(
        const unsigned int* __restrict__ cnt,
        const unsigned int* __restrict__ candbuf,
        const float* __restrict__ labels,
        const float* __restrict__ Q, const float* __restrict__ Dta,
        int* __restrict__ out, int n_total, int out_size) {
    __shared__ unsigned int cand[SEL_CAP];   // 32 KB
    __shared__ double       cval[TIE_CAP];   // 8 KB
    __shared__ unsigned int ckey[TIE_CAP];   // 4 KB
    __shared__ unsigned int red[2][3][16];
    __shared__ unsigned int tot[2][3];
    __shared__ unsigned int votes_sh, tcnt;

    const int tid = threadIdx.x;
    const int q   = blockIdx.x;

    unsigned int mraw = cnt[q];
    const int m = (int)(mraw < SEL_CAP ? mraw : SEL_CAP);
    for (int i = tid; i < m; i += SEL_T) cand[i] = candbuf[(size_t)q * SEL_CAP + i];
    if (tid == 0) { votes_sh = 0; tcnt = 0; }
    __syncthreads();

    uint32_t lo = 0, hi = 65536, base = 0;
    #pragma unroll 1
    for (int pass = 0; pass < 8; ++pass) {
        uint32_t qs = (hi - lo) >> 2;
        uint32_t p1 = lo + qs, p2 = p1 + qs, p3 = p2 + qs;
        uint32_t c1 = 0, c2 = 0, c3 = 0;
        #pragma unroll
        for (int p = 0; p < 8; ++p) {
            int idx = p * 1024 + tid;
            if (idx < m) {
                uint32_t key = cand[idx] >> 16;
                c1 += (key < p1); c2 += (key < p2); c3 += (key < p3);
            }
        }
        #pragma unroll
        for (int off = 32; off > 0; off >>= 1) {
            c1 += __shfl_down(c1, off, 64);
            c2 += __shfl_down(c2, off, 64);
            c3 += __shfl_down(c3, off, 64);
        }
        int bsel = pass & 1;
        if ((tid & 63) == 0) {
            int ww = tid >> 6;
            red[bsel][0][ww] = c1; red[bsel][1][ww] = c2; red[bsel][2][ww] = c3;
        }
        __syncthreads();
        if (tid < 48) {
            int g = tid >> 4, i = tid & 15;
            unsigned int v = red[bsel][g][i];
            v += __shfl_xor(v, 1, 64);
            v += __shfl_xor(v, 2, 64);
            v += __shfl_xor(v, 4, 64);
            v += __shfl_xor(v, 8, 64);
            if (i == 0) tot[bsel][g] = v;
        }
        __syncthreads();
        uint32_t t1 = tot[bsel][0], t2 = tot[bsel][1], t3 = tot[bsel][2];
        if      (t1 >= TOPK) { hi = p1; }
        else if (t2 >= TOPK) { lo = p1; hi = p2; base = t1; }
        else if (t3 >= TOPK) { lo = p2; hi = p3; base = t2; }
        else                 { lo = p3;          base = t3; }
    }
    const uint32_t tau    = lo;
    const uint32_t t_take = TOPK - base;

    uint32_t votes = 0;
    #pragma unroll 1
    for (int p = 0; p < 8; ++p) {
        int idx = p * 1024 + tid;
        if (idx < m) {
            uint32_t u = cand[idx];
            uint32_t key = u >> 16;
            uint32_t j   = u & 0xFFFFu;
            if (key < tau) {
                votes += (labels[j] > 0.5f) ? 1u : 0u;
            } else if (key == tau) {
                unsigned int lab = (labels[j] > 0.5f) ? 0x80000000u : 0u;
                unsigned int e = atomicAdd(&tcnt, 1u);
                if (e < TIE_CAP) {
                    const float* qp = Q   + (size_t)q * D_FEAT;
                    const float* dp = Dta + (size_t)j * D_FEAT;
                    double sacc = 0.0;
                    for (int k = 0; k < D_FEAT; ++k) {
                        double df = (double)qp[k] - (double)dp[k];
                        sacc = fma(df, df, sacc);
                    }
                    cval[e] = sacc;
                    ckey[e] = j | lab;
                }
            }
        }
    }
    #pragma unroll
    for (int off = 32; off > 0; off >>= 1)
        votes += __shfl_down(votes, off, 64);
    if ((tid & 63) == 0 && votes) atomicAdd(&votes_sh, votes);
    __syncthreads();

    unsigned int mt = tcnt; if (mt > TIE_CAP) mt = TIE_CAP;
    for (unsigned int e = tid; e < mt; e += SEL_T) {
        double       ve = cval[e];
        unsigned int ke = ckey[e];
        unsigned int ie = ke & 0x7FFFFFFFu;
        unsigned int rank = 0;
        for (unsigned int f = 0; f < mt; ++f) {
            double       vf = cval[f];
            unsigned int jf = ckey[f] & 0x7FFFFFFFu;
            rank += (vf < ve || (vf == ve && jf < ie)) ? 1u : 0u;
        }
        if (rank < t_take && (ke & 0x80000000u)) atomicAdd(&votes_sh, 1u);
    }
    __syncthreads();

    if (tid == 0) {
        out[q] = (votes_sh > TOPK / 2) ? 1 : 0;     // 64/64 tie -> class 0
        if (q == 0 && out_size > n_total) out[n_total] = 0;
    }
}

// ---------------- host ----------------
extern "C" void kernel_launch(void* const* d_in, const int* in_sizes, int n_in,
                              void* d_out, int out_size, void* d_ws, size_t ws_size,
                              hipStream_t stream) {
    const float* Q   = (const float*)d_in[0];
    const float* Dta = (const float*)d_in[1];
    const float* L   = (const float*)d_in[2];
    const int n = in_sizes[0] / D_FEAT;    // 2048
    const int N = in_sizes[1] / D_FEAT;    // 65536
    int* out = (int*)d_out;

    char* ws = (char*)d_ws;
    size_t off = 0;
    float* y2 = (float*)(ws + off);          off += (((size_t)N * 4) + 255) & ~(size_t)255;
    float* x2 = (float*)(ws + off);          off += (((size_t)n * 4) + 255) & ~(size_t)255;
    unsigned short* Asp = (unsigned short*)(ws + off); off += (((size_t)n * KSPLIT * 2) + 255) & ~(size_t)255;
    unsigned short* Bsp = (unsigned short*)(ws + off); off += (((size_t)N * KSPLIT * 2) + 255) & ~(size_t)255;
    unsigned short* skey = (unsigned short*)(ws + off); off += (((size_t)n * SAMPLE_N * 2) + 255) & ~(size_t)255;
    unsigned int* Tq  = (unsigned int*)(ws + off);    off += (((size_t)n * 4) + 255) & ~(size_t)255;
    unsigned int* cnt = (unsigned int*)(ws + off);    off += (((size_t)n * 4) + 255) & ~(size_t)255;
    unsigned int* candbuf = (unsigned int*)(ws + off);   // n * SEL_CAP * 4 = 64 MB

    hipMemsetAsync(cnt, 0, (size_t)n * 4, stream);

    sqnorm_kernel<<<dim3((N + 255) / 256), dim3(256), 0, stream>>>(Dta, y2, N);
    sqnorm_kernel<<<dim3((n + 255) / 256), dim3(256), 0, stream>>>(Q, x2, n);
    split_kernel<<<dim3(2048), dim3(256), 0, stream>>>(Q, Asp, 1, n * D_FEAT);
    split_kernel<<<dim3(2048), dim3(256), 0, stream>>>(Dta, Bsp, 0, N * D_FEAT);

    const int rowsM = n / BM;                         // 16
    dist_mfma_kernel<0><<<dim3((SAMPLE_N / BN) * rowsM), dim3(512), 0, stream>>>(
        Asp, Bsp, x2, y2, skey, nullptr, nullptr, nullptr, SAMPLE_N, rowsM);
    tsel_kernel<<<dim3(n), dim3(256), 0, stream>>>(skey, Tq);
    dist_mfma_kernel<1><<<dim3((N / BN) * rowsM), dim3(512), 0, stream>>>(
        Asp, Bsp, x2, y2, nullptr, Tq, cnt, candbuf, N, rowsM);
    select7_kernel<<<dim3(n), dim3(SEL_T), 0, stream>>>(cnt, candbuf, L, Q, Dta, out, n, out_size);
}